// Round 11
// baseline (279.554 us; speedup 1.0000x reference)
//
#include <hip/hip_runtime.h>
#include <hip/hip_bf16.h>

#define BB 64
#define TT 1024
#define AA 128
#define FF 1024
#define DQ 1024
#define DV 512

typedef __bf16 bf16x8_t __attribute__((ext_vector_type(8)));
typedef __bf16 bf16x4_t __attribute__((ext_vector_type(4)));
typedef float f32x4_t __attribute__((ext_vector_type(4)));
typedef _Float16 f16x4_t __attribute__((ext_vector_type(4)));

__device__ __forceinline__ float ftanh(float x) {
    float e = __expf(2.0f * x);
    return 1.0f - 2.0f / (e + 1.0f);
}

__device__ __forceinline__ __bf16 bhi(float x) { return (__bf16)x; }
__device__ __forceinline__ __bf16 blo(float x) {
    __bf16 h = (__bf16)x;
    return (__bf16)(x - (float)h);
}

// ---------------- K_prep ----------------
__global__ __launch_bounds__(256) void k_prep(
    const float* __restrict__ Wm, const float* __restrict__ Wconv,
    const float* __restrict__ Wloc, const float* __restrict__ query,
    const float* __restrict__ Wq,
    __bf16* __restrict__ pwmhi, __bf16* __restrict__ pwmlo,
    __bf16* __restrict__ wcthi, __bf16* __restrict__ wctlo,
    __bf16* __restrict__ pwlhi, __bf16* __restrict__ pwllo,
    float* __restrict__ q_ws) {
    __shared__ float ls[128 * 65];
    int bx = blockIdx.x, tid = threadIdx.x;
    if (bx < 16) {
        int s = bx, d0 = s * 32;
        for (int i = tid; i < 4096; i += 256) {
            int dd = i >> 7, a = i & 127;
            ls[a * 33 + dd] = Wm[(d0 + dd) * AA + a];
        }
        __syncthreads();
#pragma unroll
        for (int u = 0; u < 2; u++) {
            int pos = tid * 2 + u;                 // 0..511
            int l15 = pos & 15, lq = (pos >> 4) & 3, g = pos >> 6;
            bf16x8_t h8, l8;
#pragma unroll
            for (int j = 0; j < 8; j++) {
                float x = ls[(g * 16 + l15) * 33 + lq * 8 + j];
                h8[j] = bhi(x);
                l8[j] = blo(x);
            }
            size_t off = (size_t)(s * 512 + pos) * 8;
            *(bf16x8_t*)(pwmhi + off) = h8;
            *(bf16x8_t*)(pwmlo + off) = l8;
        }
    } else if (bx < 24) {
        int f0 = (bx - 16) * 128;
        for (int i = tid; i < 8192; i += 256) {
            int kc = i >> 7, f = i & 127;
            ls[f * 65 + kc] = (kc < 62) ? Wconv[kc * FF + f0 + f] : 0.f;
        }
        __syncthreads();
        int f = tid >> 1, half = tid & 1;
#pragma unroll
        for (int g = 0; g < 4; g++) {
            bf16x8_t h8, l8;
#pragma unroll
            for (int j = 0; j < 8; j++) {
                float x = ls[f * 65 + half * 32 + g * 8 + j];
                h8[j] = bhi(x);
                l8[j] = blo(x);
            }
            size_t off = (size_t)(f0 + f) * 64 + half * 32 + g * 8;
            *(bf16x8_t*)(wcthi + off) = h8;
            *(bf16x8_t*)(wctlo + off) = l8;
        }
    } else if (bx < 56) {
        int s2 = bx - 24, t0 = s2 * 32;
        for (int i = tid; i < 4096; i += 256) {
            int tt = i >> 7, a = i & 127;
            ls[a * 33 + tt] = Wloc[(t0 + tt) * AA + a];
        }
        __syncthreads();
#pragma unroll
        for (int u = 0; u < 2; u++) {
            int pos = tid * 2 + u;
            int l15 = pos & 15, lq = (pos >> 4) & 3, g = pos >> 6;
            bf16x8_t h8, l8;
#pragma unroll
            for (int j = 0; j < 8; j++) {
                float x = ls[(g * 16 + l15) * 33 + lq * 8 + j];
                h8[j] = bhi(x);
                l8[j] = blo(x);
            }
            size_t off = (size_t)(s2 * 512 + pos) * 8;
            *(bf16x8_t*)(pwlhi + off) = h8;
            *(bf16x8_t*)(pwllo + off) = l8;
        }
    } else {
        int b = bx - 56;
        int a = tid & 127, half = tid >> 7;
        const float* qrow = query + b * DQ + half * 512;
        float a0 = 0.f, a1 = 0.f, a2 = 0.f, a3 = 0.f;
        for (int d = 0; d < 512; d += 4) {
            float4 qv = *(const float4*)(qrow + d);
            int dg = (half * 512 + d) * AA + a;
            a0 += qv.x * Wq[dg];
            a1 += qv.y * Wq[dg + AA];
            a2 += qv.z * Wq[dg + 2 * AA];
            a3 += qv.w * Wq[dg + 3 * AA];
        }
        ls[tid] = a0 + a1 + a2 + a3;
        __syncthreads();
        if (half == 0) q_ws[b * AA + a] = ftanh(ls[a] + ls[a + 128]);
    }
}

// ---------------- K_zq: z[b][kc][a] partial sums via MFMA ----------------
// Grid 256 = 64 b x 2 a-halves x 2 k-halves (full CU coverage, 16 serial steps each).
// Output: f32 partials ztf[kh][b][a][64kc] — no bf16 pack; k_main sums planes + converts.
__global__ __launch_bounds__(256) void k_zq(
    const float* __restrict__ xcat,
    const __bf16* __restrict__ pwlhi, const __bf16* __restrict__ pwllo,
    float* __restrict__ ztf) {
    int bx = blockIdx.x;
    int b = bx & 63, ahh = (bx >> 6) & 1, kh = bx >> 7;
    int tid = threadIdx.x;
    __shared__ float xs0[1056], xs1[1056];
    __shared__ float zs[64 * 66];
    for (int i = tid; i < 1056; i += 256) {
        int t = i - 16;
        float2 xv = (t >= 0 && t < TT) ? *(const float2*)(xcat + (size_t)(b * TT + t) * 2)
                                       : make_float2(0.f, 0.f);
        xs0[i] = xv.x;
        xs1[i] = xv.y;
    }
    __syncthreads();
    int lane = tid & 63, wid = tid >> 6;
    int wm = wid >> 1, wn = wid & 1;
    int l15 = lane & 15, lq = lane >> 4;

    f32x4_t zacc[2][2];
#pragma unroll
    for (int mi = 0; mi < 2; mi++)
#pragma unroll
        for (int ni = 0; ni < 2; ni++) zacc[mi][ni] = (f32x4_t){0.f, 0.f, 0.f, 0.f};

    int phase = bx & 15;
    for (int sl = 0; sl < 16; sl++) {
        int s = kh * 16 + ((sl + phase) & 15);
        int t0 = s * 32;
        bf16x8_t bh[2], bl[2];
#pragma unroll
        for (int ni = 0; ni < 2; ni++) {
            int g = ahh * 4 + wn * 2 + ni;
            size_t poff = (size_t)((s * 8 + g) * 64 + lane) * 8;
            bh[ni] = *(const bf16x8_t*)(pwlhi + poff);
            bl[ni] = *(const bf16x8_t*)(pwllo + poff);
        }
        bf16x8_t ah_[2], al_[2];
#pragma unroll
        for (int mi = 0; mi < 2; mi++) {
            int kc = wm * 32 + mi * 16 + l15;
            const float* xsc = (kc & 1) ? xs1 : xs0;
            int base = t0 + lq * 8 + (kc >> 1) + 1;
#pragma unroll
            for (int j = 0; j < 8; j++) {
                float x = xsc[base + j];
                ah_[mi][j] = bhi(x);
                al_[mi][j] = blo(x);
            }
        }
#pragma unroll
        for (int ni = 0; ni < 2; ni++)
#pragma unroll
            for (int mi = 0; mi < 2; mi++) {
                zacc[mi][ni] = __builtin_amdgcn_mfma_f32_16x16x32_bf16(ah_[mi], bh[ni], zacc[mi][ni], 0, 0, 0);
                zacc[mi][ni] = __builtin_amdgcn_mfma_f32_16x16x32_bf16(al_[mi], bh[ni], zacc[mi][ni], 0, 0, 0);
                zacc[mi][ni] = __builtin_amdgcn_mfma_f32_16x16x32_bf16(ah_[mi], bl[ni], zacc[mi][ni], 0, 0, 0);
            }
    }
#pragma unroll
    for (int mi = 0; mi < 2; mi++)
#pragma unroll
        for (int ni = 0; ni < 2; ni++)
#pragma unroll
            for (int r = 0; r < 4; r++)
                zs[(wm * 32 + mi * 16 + lq * 4 + r) * 66 + wn * 32 + ni * 16 + l15] = zacc[mi][ni][r];
    __syncthreads();
    int a_local = tid & 63, seg = tid >> 6;   // seg: 16 kc each
#pragma unroll
    for (int g = 0; g < 2; g++) {
        f32x4_t v0, v1;
#pragma unroll
        for (int j = 0; j < 4; j++) {
            v0[j] = zs[(seg * 16 + g * 8 + j) * 66 + a_local];
            v1[j] = zs[(seg * 16 + g * 8 + 4 + j) * 66 + a_local];
        }
        float* dst = ztf + (size_t)kh * 524288 +
                     ((size_t)b * AA + ahh * 64 + a_local) * 64 + seg * 16 + g * 8;
        *(f32x4_t*)dst = v0;
        *(f32x4_t*)(dst + 4) = v1;
    }
}

// ---------------- K_main: v = tanh(value@Wm), loc = tanh(wct@z), fused score ----------------
// BM=64 x BN=128 x BK=32, grid 1024 (64 b x 16 t-slices), 4 waves 2x2 (each 32x64).
// All-LDS staging (R7 mechanism, 81us at BM=128/2 blocks/CU): A pre-swizzled f32 +
// B fragment-linear hi/lo via global_load_lds, double-buffered. Halved tile -> LDS
// 48.5KB -> 3 blocks/CU = 12 waves/CU (1.5x R7/R10's 8): attacks the ~60us wait that
// three structurally different k_mains all showed at 2 blocks/CU. Runtime loop (LDS is
// runtime-indexable; no asm reg buffers -> rule #20 n/a, small I$ footprint).
__global__ __launch_bounds__(256, 3) void k_main(
    const float* __restrict__ value,
    const __bf16* __restrict__ pwmhi, const __bf16* __restrict__ pwmlo,
    const __bf16* __restrict__ wcthi, const __bf16* __restrict__ wctlo,
    const float* __restrict__ ztf,
    const float* __restrict__ q_ws, const float* __restrict__ Wv,
    _Float16* __restrict__ v_ws, float* __restrict__ score) {
    int b = blockIdx.x >> 4;
    int trow0 = (blockIdx.x & 15) << 6;
    int tid = threadIdx.x;
    int lane = tid & 63, wid = tid >> 6;
    int wm = wid >> 1, wn = wid & 1;
    int l15 = lane & 15, lq = lane >> 4;
    int phase = (blockIdx.x + (blockIdx.x >> 4)) & 15;

    __shared__ __align__(16) float As[2][64 * 32];      // 8 KB per buf
    __shared__ __align__(16) __bf16 Bh[2][512 * 8];     // 8 KB per buf
    __shared__ __align__(16) __bf16 Bl[2][512 * 8];     // 8 KB per buf
    __shared__ float sc_red[128];

    f32x4_t acc[2][4];
#pragma unroll
    for (int mi = 0; mi < 2; mi++)
#pragma unroll
        for (int ni = 0; ni < 4; ni++) acc[mi][ni] = (f32x4_t){0.f, 0.f, 0.f, 0.f};

    // A staging: instr i (0..1): chunk c=i*256+tid -> row=i*32+(tid>>3), unit u=tid&7.
    // Pre-swizzled global unit = u ^ (row&7); LDS[row][u] = global[row][u^(row&7)].
    int su = (tid & 7) ^ ((tid >> 3) & 7);
    const float* aG[2];
    unsigned aL[2];
#pragma unroll
    for (int i = 0; i < 2; i++) {
        int row = i * 32 + (tid >> 3);
        aG[i] = value + (size_t)(b * TT + trow0 + row) * DV + su * 4;
        aL[i] = (unsigned)((i * 256 + tid) * 16);
    }
    // B staging: chunk c=i*256+tid; source pwm* + s*4096 + c*8 elements (linear).
    unsigned bOffE = (unsigned)tid * 8;        // element offset of chunk tid
    unsigned bLB = (unsigned)tid * 16;         // byte offset in B buf

#define STAGE(bf, s)                                                                         \
    {                                                                                        \
        _Pragma("unroll") for (int i = 0; i < 2; i++)                                        \
            __builtin_amdgcn_global_load_lds(                                                \
                (const __attribute__((address_space(1))) void*)(aG[i] + (size_t)(s) * 32),   \
                (__attribute__((address_space(3))) void*)((char*)&As[bf][0] + aL[i]),        \
                16, 0, 0);                                                                   \
        _Pragma("unroll") for (int i = 0; i < 2; i++) {                                      \
            __builtin_amdgcn_global_load_lds(                                                \
                (const __attribute__((address_space(1))) void*)(pwmhi + (size_t)(s) * 4096 + bOffE + i * 2048), \
                (__attribute__((address_space(3))) void*)((char*)&Bh[bf][0] + bLB + i * 4096),                  \
                16, 0, 0);                                                                   \
            __builtin_amdgcn_global_load_lds(                                                \
                (const __attribute__((address_space(1))) void*)(pwmlo + (size_t)(s) * 4096 + bOffE + i * 2048), \
                (__attribute__((address_space(3))) void*)((char*)&Bl[bf][0] + bLB + i * 4096),                  \
                16, 0, 0);                                                                   \
        }                                                                                    \
    }

    STAGE(0, phase);
    __syncthreads();   // vmcnt(0) drain + barrier

    int swz = l15 & 7;  // read-side row XOR key (row&7 == l15&7 for all frag rows)
    for (int it = 0; it < 16; ++it) {
        int cb = it & 1;
        if (it < 15) STAGE(cb ^ 1, (it + 1 + phase) & 15);   // lands by next barrier

        // A fragments: row = wm*32 + mi*16 + l15; logical unit g=lq*2+k at physical g^swz
        bf16x8_t ah[2], al[2];
#pragma unroll
        for (int mi = 0; mi < 2; mi++) {
            int row = wm * 32 + mi * 16 + l15;
            const char* rbase = (const char*)&As[cb][0] + row * 128;
            f32x4_t f0 = *(const f32x4_t*)(rbase + (((lq * 2 + 0) ^ swz) << 4));
            f32x4_t f1 = *(const f32x4_t*)(rbase + (((lq * 2 + 1) ^ swz) << 4));
#pragma unroll
            for (int j = 0; j < 4; j++) {
                ah[mi][j] = bhi(f0[j]);
                al[mi][j] = blo(f0[j]);
                ah[mi][4 + j] = bhi(f1[j]);
                al[mi][4 + j] = blo(f1[j]);
            }
        }
        // B fragments: fragment-linear chunks
        bf16x8_t bh[4], bl[4];
#pragma unroll
        for (int ni = 0; ni < 4; ni++) {
            int c = (wn * 4 + ni) * 64 + lane;
            bh[ni] = *(const bf16x8_t*)(&Bh[cb][0] + (size_t)c * 8);
            bl[ni] = *(const bf16x8_t*)(&Bl[cb][0] + (size_t)c * 8);
        }
#pragma unroll
        for (int mi = 0; mi < 2; mi++)
#pragma unroll
            for (int ni = 0; ni < 4; ni++) {
                acc[mi][ni] = __builtin_amdgcn_mfma_f32_16x16x32_bf16(ah[mi], bh[ni], acc[mi][ni], 0, 0, 0);
                acc[mi][ni] = __builtin_amdgcn_mfma_f32_16x16x32_bf16(al[mi], bh[ni], acc[mi][ni], 0, 0, 0);
                acc[mi][ni] = __builtin_amdgcn_mfma_f32_16x16x32_bf16(ah[mi], bl[ni], acc[mi][ni], 0, 0, 0);
            }
        __syncthreads();  // drains the stage issued this iteration; next iter reads cb^1
    }
#undef STAGE

    // ---- loc gemm: K=64, kc 62/63 zero-padded in wct; z from f32 partial planes ----
    f32x4_t lacc[2][4];
#pragma unroll
    for (int mi = 0; mi < 2; mi++)
#pragma unroll
        for (int ni = 0; ni < 4; ni++) lacc[mi][ni] = (f32x4_t){0.f, 0.f, 0.f, 0.f};
#pragma unroll
    for (int kc0 = 0; kc0 < 64; kc0 += 32) {
        bf16x8_t a2h[2], a2l[2], b2h[4], b2l[4];
#pragma unroll
        for (int mi = 0; mi < 2; mi++) {
            int f = trow0 + wm * 32 + mi * 16 + l15;
            a2h[mi] = *(const bf16x8_t*)(wcthi + (size_t)f * 64 + kc0 + lq * 8);
            a2l[mi] = *(const bf16x8_t*)(wctlo + (size_t)f * 64 + kc0 + lq * 8);
        }
#pragma unroll
        for (int ni = 0; ni < 4; ni++) {
            int a = wn * 64 + ni * 16 + l15;
            const float* zp = ztf + ((size_t)b * AA + a) * 64 + kc0 + lq * 8;
            f32x4_t z0 = *(const f32x4_t*)zp + *(const f32x4_t*)(zp + 524288);
            f32x4_t z1 = *(const f32x4_t*)(zp + 4) + *(const f32x4_t*)(zp + 524292);
#pragma unroll
            for (int j = 0; j < 4; j++) {
                b2h[ni][j] = bhi(z0[j]);
                b2l[ni][j] = blo(z0[j]);
                b2h[ni][4 + j] = bhi(z1[j]);
                b2l[ni][4 + j] = blo(z1[j]);
            }
        }
#pragma unroll
        for (int mi = 0; mi < 2; mi++)
#pragma unroll
            for (int ni = 0; ni < 4; ni++) {
                lacc[mi][ni] = __builtin_amdgcn_mfma_f32_16x16x32_bf16(a2h[mi], b2h[ni], lacc[mi][ni], 0, 0, 0);
                lacc[mi][ni] = __builtin_amdgcn_mfma_f32_16x16x32_bf16(a2l[mi], b2h[ni], lacc[mi][ni], 0, 0, 0);
                lacc[mi][ni] = __builtin_amdgcn_mfma_f32_16x16x32_bf16(a2h[mi], b2l[ni], lacc[mi][ni], 0, 0, 0);
            }
    }

    // ---- epilogue ----
    float qv[4], wv[4];
#pragma unroll
    for (int ni = 0; ni < 4; ni++) {
        int a = wn * 64 + ni * 16 + l15;
        qv[ni] = q_ws[b * AA + a];
        wv[ni] = Wv[a];
    }
#pragma unroll
    for (int mi = 0; mi < 2; mi++) {
#pragma unroll
        for (int r = 0; r < 4; r++) {
            int tl = wm * 32 + mi * 16 + lq * 4 + r;
            int t = trow0 + tl;
            float s = 0.f;
#pragma unroll
            for (int ni = 0; ni < 4; ni++) {
                float v = ftanh(acc[mi][ni][r]);
                float loc = ftanh(lacc[mi][ni][r]);
                int a = wn * 64 + ni * 16 + l15;
                v_ws[(size_t)(b * TT + t) * AA + a] = (_Float16)v;
                s += ftanh(qv[ni] + v + loc) * wv[ni];
            }
            s += __shfl_xor(s, 1, 64);
            s += __shfl_xor(s, 2, 64);
            s += __shfl_xor(s, 4, 64);
            s += __shfl_xor(s, 8, 64);
            if (l15 == 0) sc_red[wn * 64 + tl] = s;
        }
    }
    __syncthreads();
    if (tid < 64) score[b * TT + trow0 + tid] = sc_red[tid] + sc_red[64 + tid];
}

// ---------------- K_softmax (also zeroes out_ctx, replacing the memset dispatch) ----------------
__global__ void k_softmax(const float* __restrict__ score, float* __restrict__ out_align,
                          float* __restrict__ out_ctx) {
    int b = blockIdx.x, tid = threadIdx.x;
    if (tid < 128) out_ctx[b * AA + tid] = 0.f;   // k_context (later launch) atomicAdds
    __shared__ float red[4];
    float s[4];
#pragma unroll
    for (int i = 0; i < 4; i++) s[i] = score[b * TT + tid + i * 256];
    float m = fmaxf(fmaxf(s[0], s[1]), fmaxf(s[2], s[3]));
    for (int off = 32; off; off >>= 1) m = fmaxf(m, __shfl_xor(m, off, 64));
    int wid = tid >> 6;
    if ((tid & 63) == 0) red[wid] = m;
    __syncthreads();
    float M = fmaxf(fmaxf(red[0], red[1]), fmaxf(red[2], red[3]));
    __syncthreads();
    float e[4];
    float sum = 0.f;
#pragma unroll
    for (int i = 0; i < 4; i++) { e[i] = __expf(s[i] - M); sum += e[i]; }
    for (int off = 32; off; off >>= 1) sum += __shfl_xor(sum, off, 64);
    if ((tid & 63) == 0) red[wid] = sum;
    __syncthreads();
    float inv = 1.0f / (red[0] + red[1] + red[2] + red[3]);
#pragma unroll
    for (int i = 0; i < 4; i++) out_align[b * TT + tid + i * 256] = e[i] * inv;
}

// ---------------- K_context: context[b,a] = sum_t align[b,t] * v[b,t,a] (v in f16) ----------------
__global__ void k_context(const float* __restrict__ align, const _Float16* __restrict__ v_ws,
                          float* __restrict__ out_ctx) {
    int b = blockIdx.y, t0 = blockIdx.x * 64, tid = threadIdx.x;
    int a0 = (tid & 31) * 4, tl = tid >> 5;
    __shared__ float sh[8 * 132];
    f32x4_t acc = (f32x4_t){0.f, 0.f, 0.f, 0.f};
    for (int tt = tl; tt < 64; tt += 8) {
        float w = align[b * TT + t0 + tt];
        f16x4_t vv = *(const f16x4_t*)(v_ws + (size_t)(b * TT + t0 + tt) * AA + a0);
        acc[0] += w * (float)vv[0];
        acc[1] += w * (float)vv[1];
        acc[2] += w * (float)vv[2];
        acc[3] += w * (float)vv[3];
    }
    *(f32x4_t*)&sh[tl * 132 + a0] = acc;
    __syncthreads();
    if (tid < 128) {
        float s = 0.f;
#pragma unroll
        for (int j = 0; j < 8; j++) s += sh[j * 132 + tid];
        atomicAdd(out_ctx + b * AA + tid, s);
    }
}

extern "C" void kernel_launch(void* const* d_in, const int* in_sizes, int n_in,
                              void* d_out, int out_size, void* d_ws, size_t ws_size,
                              hipStream_t stream) {
    const float* query = (const float*)d_in[0];
    const float* value = (const float*)d_in[1];
    const float* xcat  = (const float*)d_in[2];
    const float* Wq    = (const float*)d_in[3];
    const float* Wm    = (const float*)d_in[4];
    const float* Wv    = (const float*)d_in[5];
    const float* Wconv = (const float*)d_in[6];
    const float* Wloc  = (const float*)d_in[7];
    float* out = (float*)d_out;

    float* ws = (float*)d_ws;
    float* q_ws  = ws;                            // 8192 f
    float* sc_ws = q_ws + 8192;                   // 65536 f
    _Float16* v_ws = (_Float16*)(sc_ws + 65536);  // 8388608 halfs = 4194304 f
    __bf16* pwmhi = (__bf16*)(sc_ws + 65536 + 4194304);
    __bf16* pwmlo = pwmhi + 65536;
    __bf16* wcthi = pwmlo + 65536;
    __bf16* wctlo = wcthi + 65536;
    __bf16* pwlhi = wctlo + 65536;                // 131072
    __bf16* pwllo = pwlhi + 131072;
    float* ztf = (float*)(pwllo + 131072);        // 2 planes x 524288 f32 (4 MB)

    k_prep<<<120, 256, 0, stream>>>(Wm, Wconv, Wloc, query, Wq,
                                    pwmhi, pwmlo, wcthi, wctlo, pwlhi, pwllo, q_ws);
    k_zq<<<256, 256, 0, stream>>>(xcat, pwlhi, pwllo, ztf);
    k_main<<<1024, 256, 0, stream>>>(value, pwmhi, pwmlo, wcthi, wctlo, ztf,
                                     q_ws, Wv, v_ws, sc_ws);
    k_softmax<<<BB, 256, 0, stream>>>(sc_ws, out + 8192, out);
    k_context<<<dim3(16, BB), 256, 0, stream>>>(out + 8192, v_ws, out);
}

// Round 12
// 266.044 us; speedup vs baseline: 1.0508x; 1.0508x over previous
//
#include <hip/hip_runtime.h>
#include <hip/hip_bf16.h>

#define BB 64
#define TT 1024
#define AA 128
#define FF 1024
#define DQ 1024
#define DV 512

typedef __bf16 bf16x8_t __attribute__((ext_vector_type(8)));
typedef __bf16 bf16x4_t __attribute__((ext_vector_type(4)));
typedef float f32x4_t __attribute__((ext_vector_type(4)));
typedef _Float16 f16x4_t __attribute__((ext_vector_type(4)));

__device__ __forceinline__ float ftanh(float x) {
    float e = __expf(2.0f * x);
    return 1.0f - 2.0f / (e + 1.0f);
}

__device__ __forceinline__ __bf16 bhi(float x) { return (__bf16)x; }
__device__ __forceinline__ __bf16 blo(float x) {
    __bf16 h = (__bf16)x;
    return (__bf16)(x - (float)h);
}

// ---------------- K_prep ----------------
__global__ __launch_bounds__(256) void k_prep(
    const float* __restrict__ Wm, const float* __restrict__ Wconv,
    const float* __restrict__ Wloc, const float* __restrict__ query,
    const float* __restrict__ Wq,
    __bf16* __restrict__ pwmhi, __bf16* __restrict__ pwmlo,
    __bf16* __restrict__ wcthi, __bf16* __restrict__ wctlo,
    __bf16* __restrict__ pwlhi, __bf16* __restrict__ pwllo,
    float* __restrict__ q_ws) {
    __shared__ float ls[128 * 65];
    int bx = blockIdx.x, tid = threadIdx.x;
    if (bx < 16) {
        int s = bx, d0 = s * 32;
        for (int i = tid; i < 4096; i += 256) {
            int dd = i >> 7, a = i & 127;
            ls[a * 33 + dd] = Wm[(d0 + dd) * AA + a];
        }
        __syncthreads();
#pragma unroll
        for (int u = 0; u < 2; u++) {
            int pos = tid * 2 + u;                 // 0..511
            int l15 = pos & 15, lq = (pos >> 4) & 3, g = pos >> 6;
            bf16x8_t h8, l8;
#pragma unroll
            for (int j = 0; j < 8; j++) {
                float x = ls[(g * 16 + l15) * 33 + lq * 8 + j];
                h8[j] = bhi(x);
                l8[j] = blo(x);
            }
            size_t off = (size_t)(s * 512 + pos) * 8;
            *(bf16x8_t*)(pwmhi + off) = h8;
            *(bf16x8_t*)(pwmlo + off) = l8;
        }
    } else if (bx < 24) {
        int f0 = (bx - 16) * 128;
        for (int i = tid; i < 8192; i += 256) {
            int kc = i >> 7, f = i & 127;
            ls[f * 65 + kc] = (kc < 62) ? Wconv[kc * FF + f0 + f] : 0.f;
        }
        __syncthreads();
        int f = tid >> 1, half = tid & 1;
#pragma unroll
        for (int g = 0; g < 4; g++) {
            bf16x8_t h8, l8;
#pragma unroll
            for (int j = 0; j < 8; j++) {
                float x = ls[f * 65 + half * 32 + g * 8 + j];
                h8[j] = bhi(x);
                l8[j] = blo(x);
            }
            size_t off = (size_t)(f0 + f) * 64 + half * 32 + g * 8;
            *(bf16x8_t*)(wcthi + off) = h8;
            *(bf16x8_t*)(wctlo + off) = l8;
        }
    } else if (bx < 56) {
        int s2 = bx - 24, t0 = s2 * 32;
        for (int i = tid; i < 4096; i += 256) {
            int tt = i >> 7, a = i & 127;
            ls[a * 33 + tt] = Wloc[(t0 + tt) * AA + a];
        }
        __syncthreads();
#pragma unroll
        for (int u = 0; u < 2; u++) {
            int pos = tid * 2 + u;
            int l15 = pos & 15, lq = (pos >> 4) & 3, g = pos >> 6;
            bf16x8_t h8, l8;
#pragma unroll
            for (int j = 0; j < 8; j++) {
                float x = ls[(g * 16 + l15) * 33 + lq * 8 + j];
                h8[j] = bhi(x);
                l8[j] = blo(x);
            }
            size_t off = (size_t)(s2 * 512 + pos) * 8;
            *(bf16x8_t*)(pwlhi + off) = h8;
            *(bf16x8_t*)(pwllo + off) = l8;
        }
    } else {
        int b = bx - 56;
        int a = tid & 127, half = tid >> 7;
        const float* qrow = query + b * DQ + half * 512;
        float a0 = 0.f, a1 = 0.f, a2 = 0.f, a3 = 0.f;
        for (int d = 0; d < 512; d += 4) {
            float4 qv = *(const float4*)(qrow + d);
            int dg = (half * 512 + d) * AA + a;
            a0 += qv.x * Wq[dg];
            a1 += qv.y * Wq[dg + AA];
            a2 += qv.z * Wq[dg + 2 * AA];
            a3 += qv.w * Wq[dg + 3 * AA];
        }
        ls[tid] = a0 + a1 + a2 + a3;
        __syncthreads();
        if (half == 0) q_ws[b * AA + a] = ftanh(ls[a] + ls[a + 128]);
    }
}

// ---------------- K_zq: z[b][kc][a] partial sums via MFMA ----------------
__global__ __launch_bounds__(256) void k_zq(
    const float* __restrict__ xcat,
    const __bf16* __restrict__ pwlhi, const __bf16* __restrict__ pwllo,
    float* __restrict__ ztf) {
    int bx = blockIdx.x;
    int b = bx & 63, ahh = (bx >> 6) & 1, kh = bx >> 7;
    int tid = threadIdx.x;
    __shared__ float xs0[1056], xs1[1056];
    __shared__ float zs[64 * 66];
    for (int i = tid; i < 1056; i += 256) {
        int t = i - 16;
        float2 xv = (t >= 0 && t < TT) ? *(const float2*)(xcat + (size_t)(b * TT + t) * 2)
                                       : make_float2(0.f, 0.f);
        xs0[i] = xv.x;
        xs1[i] = xv.y;
    }
    __syncthreads();
    int lane = tid & 63, wid = tid >> 6;
    int wm = wid >> 1, wn = wid & 1;
    int l15 = lane & 15, lq = lane >> 4;

    f32x4_t zacc[2][2];
#pragma unroll
    for (int mi = 0; mi < 2; mi++)
#pragma unroll
        for (int ni = 0; ni < 2; ni++) zacc[mi][ni] = (f32x4_t){0.f, 0.f, 0.f, 0.f};

    int phase = bx & 15;
    for (int sl = 0; sl < 16; sl++) {
        int s = kh * 16 + ((sl + phase) & 15);
        int t0 = s * 32;
        bf16x8_t bh[2], bl[2];
#pragma unroll
        for (int ni = 0; ni < 2; ni++) {
            int g = ahh * 4 + wn * 2 + ni;
            size_t poff = (size_t)((s * 8 + g) * 64 + lane) * 8;
            bh[ni] = *(const bf16x8_t*)(pwlhi + poff);
            bl[ni] = *(const bf16x8_t*)(pwllo + poff);
        }
        bf16x8_t ah_[2], al_[2];
#pragma unroll
        for (int mi = 0; mi < 2; mi++) {
            int kc = wm * 32 + mi * 16 + l15;
            const float* xsc = (kc & 1) ? xs1 : xs0;
            int base = t0 + lq * 8 + (kc >> 1) + 1;
#pragma unroll
            for (int j = 0; j < 8; j++) {
                float x = xsc[base + j];
                ah_[mi][j] = bhi(x);
                al_[mi][j] = blo(x);
            }
        }
#pragma unroll
        for (int ni = 0; ni < 2; ni++)
#pragma unroll
            for (int mi = 0; mi < 2; mi++) {
                zacc[mi][ni] = __builtin_amdgcn_mfma_f32_16x16x32_bf16(ah_[mi], bh[ni], zacc[mi][ni], 0, 0, 0);
                zacc[mi][ni] = __builtin_amdgcn_mfma_f32_16x16x32_bf16(al_[mi], bh[ni], zacc[mi][ni], 0, 0, 0);
                zacc[mi][ni] = __builtin_amdgcn_mfma_f32_16x16x32_bf16(ah_[mi], bl[ni], zacc[mi][ni], 0, 0, 0);
            }
    }
#pragma unroll
    for (int mi = 0; mi < 2; mi++)
#pragma unroll
        for (int ni = 0; ni < 2; ni++)
#pragma unroll
            for (int r = 0; r < 4; r++)
                zs[(wm * 32 + mi * 16 + lq * 4 + r) * 66 + wn * 32 + ni * 16 + l15] = zacc[mi][ni][r];
    __syncthreads();
    int a_local = tid & 63, seg = tid >> 6;   // seg: 16 kc each
#pragma unroll
    for (int g = 0; g < 2; g++) {
        f32x4_t v0, v1;
#pragma unroll
        for (int j = 0; j < 4; j++) {
            v0[j] = zs[(seg * 16 + g * 8 + j) * 66 + a_local];
            v1[j] = zs[(seg * 16 + g * 8 + 4 + j) * 66 + a_local];
        }
        float* dst = ztf + (size_t)kh * 524288 +
                     ((size_t)b * AA + ahh * 64 + a_local) * 64 + seg * 16 + g * 8;
        *(f32x4_t*)dst = v0;
        *(f32x4_t*)(dst + 4) = v1;
    }
}

// ---------------- K_main: v = tanh(value@Wm), loc = tanh(wct@z), fused score ----------------
// R7 structure (BM=128xBN=128, 512 blocks, A+B LDS-staged dbuf — best measured 81us) with
// the T4 counted-vmcnt schedule replacing __syncthreads: per iteration
//   STAGE(it+1) -> s_waitcnt vmcnt(8) -> s_barrier -> reads/MFMA -> lgkmcnt(0) -> s_barrier
// vmcnt(8) retires exactly stage(it) (issued a FULL iteration ago, latency hidden) while
// stage(it+1)'s 8 loads stay in flight — never vmcnt(0) in the loop (R7/R10/R11 all paid
// a just-issued-stage drain every iteration; 3 structures, same ~55us wait).
// Race audit: stage(it+1) writes buf[nxt]; its readers are iteration it-1, separated by
// it-1's end-barrier. Reads of buf[cur] at it vs stage(it+2) writing buf[cur] separated
// by it's end-barrier. sched_barrier(0) fences both sites (rule #18).
__global__ __launch_bounds__(256, 2) void k_main(
    const float* __restrict__ value,
    const __bf16* __restrict__ pwmhi, const __bf16* __restrict__ pwmlo,
    const __bf16* __restrict__ wcthi, const __bf16* __restrict__ wctlo,
    const float* __restrict__ ztf,
    const float* __restrict__ q_ws, const float* __restrict__ Wv,
    _Float16* __restrict__ v_ws, float* __restrict__ score) {
    int b = blockIdx.x >> 3;
    int trow0 = (blockIdx.x & 7) << 7;
    int tid = threadIdx.x;
    int lane = tid & 63, wid = tid >> 6;
    int wm = wid >> 1, wn = wid & 1;
    int l15 = lane & 15, lq = lane >> 4;
    int phase = (blockIdx.x + (blockIdx.x >> 3)) & 15;

    __shared__ __align__(16) float As[2][128 * 32];     // 16 KB per buf
    __shared__ __align__(16) __bf16 Bh[2][512 * 8];     // 8 KB per buf
    __shared__ __align__(16) __bf16 Bl[2][512 * 8];     // 8 KB per buf
    __shared__ float sc_red[256];

    f32x4_t acc[4][4];
#pragma unroll
    for (int mi = 0; mi < 4; mi++)
#pragma unroll
        for (int ni = 0; ni < 4; ni++) acc[mi][ni] = (f32x4_t){0.f, 0.f, 0.f, 0.f};

    // A staging: instr i (0..3): chunk c=(wid*4+i)*64+lane -> row=(wid*4+i)*8+(lane>>3),
    // unit u=lane&7; pre-swizzled global unit = u ^ (row&7) = u ^ (lane>>3).
    int l3 = lane >> 3;
    int su = (lane & 7) ^ l3;
    const float* aG[4];
    unsigned aL[4];
#pragma unroll
    for (int i = 0; i < 4; i++) {
        int row = (wid * 4 + i) * 8 + l3;
        aG[i] = value + (size_t)(b * TT + trow0 + row) * DV + su * 4;
        aL[i] = (unsigned)((wid * 4 + i) * 1024);
    }
    // B staging: instr j (0..1): chunk c=(wid*2+j)*64+lane, fragment-linear
    const __bf16* bGh[2];
    const __bf16* bGl[2];
    unsigned bL[2];
#pragma unroll
    for (int j = 0; j < 2; j++) {
        int c = (wid * 2 + j) * 64 + lane;
        bGh[j] = pwmhi + (size_t)c * 8;
        bGl[j] = pwmlo + (size_t)c * 8;
        bL[j] = (unsigned)((wid * 2 + j) * 1024);
    }

#define STAGE(bf, s)                                                                        \
    {                                                                                       \
        _Pragma("unroll") for (int i = 0; i < 4; i++)                                       \
            __builtin_amdgcn_global_load_lds(                                               \
                (const __attribute__((address_space(1))) void*)(aG[i] + (size_t)(s) * 32),  \
                (__attribute__((address_space(3))) void*)((char*)&As[bf][0] + aL[i]),       \
                16, 0, 0);                                                                  \
        _Pragma("unroll") for (int j = 0; j < 2; j++) {                                     \
            __builtin_amdgcn_global_load_lds(                                               \
                (const __attribute__((address_space(1))) void*)(bGh[j] + (size_t)(s) * 4096),\
                (__attribute__((address_space(3))) void*)((char*)&Bh[bf][0] + bL[j]),       \
                16, 0, 0);                                                                  \
            __builtin_amdgcn_global_load_lds(                                               \
                (const __attribute__((address_space(1))) void*)(bGl[j] + (size_t)(s) * 4096),\
                (__attribute__((address_space(3))) void*)((char*)&Bl[bf][0] + bL[j]),       \
                16, 0, 0);                                                                  \
        }                                                                                   \
    }

    STAGE(0, phase);   // stage(0): 8 loads in flight

    int swz = l15 & 7;  // read-side row XOR key
    for (int it = 0; it < 16; ++it) {
        int cb = it & 1;
        if (it < 15) {
            STAGE(cb ^ 1, (it + 1 + phase) & 15);      // +8 loads (total 16 outstanding)
            asm volatile("s_waitcnt vmcnt(8)");         // retire stage(it); stage(it+1) flies
        } else {
            asm volatile("s_waitcnt vmcnt(0)");         // final drain
        }
        __builtin_amdgcn_s_barrier();                   // all waves' stage(it) landed
        __builtin_amdgcn_sched_barrier(0);              // rule #18: no hoisting above

        // A fragments: row = wm*64+mi*16+l15; logical unit g=lq*2+k at physical g^swz
        bf16x8_t ah[4], al[4];
#pragma unroll
        for (int mi = 0; mi < 4; mi++) {
            int row = wm * 64 + mi * 16 + l15;
            const char* rbase = (const char*)&As[cb][0] + row * 128;
            f32x4_t f0 = *(const f32x4_t*)(rbase + (((lq * 2 + 0) ^ swz) << 4));
            f32x4_t f1 = *(const f32x4_t*)(rbase + (((lq * 2 + 1) ^ swz) << 4));
#pragma unroll
            for (int j = 0; j < 4; j++) {
                ah[mi][j] = bhi(f0[j]);
                al[mi][j] = blo(f0[j]);
                ah[mi][4 + j] = bhi(f1[j]);
                al[mi][4 + j] = blo(f1[j]);
            }
        }
        // B fragments: fragment-linear chunks
        bf16x8_t bh[4], bl[4];
#pragma unroll
        for (int ni = 0; ni < 4; ni++) {
            int c = (wn * 4 + ni) * 64 + lane;
            bh[ni] = *(const bf16x8_t*)(&Bh[cb][0] + (size_t)c * 8);
            bl[ni] = *(const bf16x8_t*)(&Bl[cb][0] + (size_t)c * 8);
        }
#pragma unroll
        for (int mi = 0; mi < 4; mi++)
#pragma unroll
            for (int ni = 0; ni < 4; ni++) {
                acc[mi][ni] = __builtin_amdgcn_mfma_f32_16x16x32_bf16(ah[mi], bh[ni], acc[mi][ni], 0, 0, 0);
                acc[mi][ni] = __builtin_amdgcn_mfma_f32_16x16x32_bf16(al[mi], bh[ni], acc[mi][ni], 0, 0, 0);
                acc[mi][ni] = __builtin_amdgcn_mfma_f32_16x16x32_bf16(ah[mi], bl[ni], acc[mi][ni], 0, 0, 0);
            }
        __builtin_amdgcn_sched_barrier(0);
        asm volatile("s_waitcnt lgkmcnt(0)");           // reads of buf cb retired
        __builtin_amdgcn_s_barrier();                   // before next overwrite of buf cb
    }
#undef STAGE

    // ---- loc gemm: K=64, kc 62/63 zero-padded in wct; z from f32 partial planes ----
    f32x4_t lacc[4][4];
#pragma unroll
    for (int mi = 0; mi < 4; mi++)
#pragma unroll
        for (int ni = 0; ni < 4; ni++) lacc[mi][ni] = (f32x4_t){0.f, 0.f, 0.f, 0.f};
#pragma unroll
    for (int kc0 = 0; kc0 < 64; kc0 += 32) {
        bf16x8_t a2h[4], a2l[4], b2h[4], b2l[4];
#pragma unroll
        for (int mi = 0; mi < 4; mi++) {
            int f = trow0 + wm * 64 + mi * 16 + l15;
            a2h[mi] = *(const bf16x8_t*)(wcthi + (size_t)f * 64 + kc0 + lq * 8);
            a2l[mi] = *(const bf16x8_t*)(wctlo + (size_t)f * 64 + kc0 + lq * 8);
        }
#pragma unroll
        for (int ni = 0; ni < 4; ni++) {
            int a = wn * 64 + ni * 16 + l15;
            const float* zp = ztf + ((size_t)b * AA + a) * 64 + kc0 + lq * 8;
            f32x4_t z0 = *(const f32x4_t*)zp + *(const f32x4_t*)(zp + 524288);
            f32x4_t z1 = *(const f32x4_t*)(zp + 4) + *(const f32x4_t*)(zp + 524292);
#pragma unroll
            for (int j = 0; j < 4; j++) {
                b2h[ni][j] = bhi(z0[j]);
                b2l[ni][j] = blo(z0[j]);
                b2h[ni][4 + j] = bhi(z1[j]);
                b2l[ni][4 + j] = blo(z1[j]);
            }
        }
#pragma unroll
        for (int mi = 0; mi < 4; mi++)
#pragma unroll
            for (int ni = 0; ni < 4; ni++) {
                lacc[mi][ni] = __builtin_amdgcn_mfma_f32_16x16x32_bf16(a2h[mi], b2h[ni], lacc[mi][ni], 0, 0, 0);
                lacc[mi][ni] = __builtin_amdgcn_mfma_f32_16x16x32_bf16(a2l[mi], b2h[ni], lacc[mi][ni], 0, 0, 0);
                lacc[mi][ni] = __builtin_amdgcn_mfma_f32_16x16x32_bf16(a2h[mi], b2l[ni], lacc[mi][ni], 0, 0, 0);
            }
    }

    // ---- epilogue ----
    float qv[4], wv[4];
#pragma unroll
    for (int ni = 0; ni < 4; ni++) {
        int a = wn * 64 + ni * 16 + l15;
        qv[ni] = q_ws[b * AA + a];
        wv[ni] = Wv[a];
    }
#pragma unroll
    for (int mi = 0; mi < 4; mi++) {
#pragma unroll
        for (int r = 0; r < 4; r++) {
            int tl = wm * 64 + mi * 16 + lq * 4 + r;
            int t = trow0 + tl;
            float s = 0.f;
#pragma unroll
            for (int ni = 0; ni < 4; ni++) {
                float v = ftanh(acc[mi][ni][r]);
                float loc = ftanh(lacc[mi][ni][r]);
                int a = wn * 64 + ni * 16 + l15;
                v_ws[(size_t)(b * TT + t) * AA + a] = (_Float16)v;
                s += ftanh(qv[ni] + v + loc) * wv[ni];
            }
            s += __shfl_xor(s, 1, 64);
            s += __shfl_xor(s, 2, 64);
            s += __shfl_xor(s, 4, 64);
            s += __shfl_xor(s, 8, 64);
            if (l15 == 0) sc_red[wn * 128 + tl] = s;
        }
    }
    __syncthreads();
    if (tid < 128) score[b * TT + trow0 + tid] = sc_red[tid] + sc_red[128 + tid];
}

// ---------------- K_softmax (also zeroes out_ctx, replacing the memset dispatch) ----------------
__global__ void k_softmax(const float* __restrict__ score, float* __restrict__ out_align,
                          float* __restrict__ out_ctx) {
    int b = blockIdx.x, tid = threadIdx.x;
    if (tid < 128) out_ctx[b * AA + tid] = 0.f;   // k_context (later launch) atomicAdds
    __shared__ float red[4];
    float s[4];
#pragma unroll
    for (int i = 0; i < 4; i++) s[i] = score[b * TT + tid + i * 256];
    float m = fmaxf(fmaxf(s[0], s[1]), fmaxf(s[2], s[3]));
    for (int off = 32; off; off >>= 1) m = fmaxf(m, __shfl_xor(m, off, 64));
    int wid = tid >> 6;
    if ((tid & 63) == 0) red[wid] = m;
    __syncthreads();
    float M = fmaxf(fmaxf(red[0], red[1]), fmaxf(red[2], red[3]));
    __syncthreads();
    float e[4];
    float sum = 0.f;
#pragma unroll
    for (int i = 0; i < 4; i++) { e[i] = __expf(s[i] - M); sum += e[i]; }
    for (int off = 32; off; off >>= 1) sum += __shfl_xor(sum, off, 64);
    if ((tid & 63) == 0) red[wid] = sum;
    __syncthreads();
    float inv = 1.0f / (red[0] + red[1] + red[2] + red[3]);
#pragma unroll
    for (int i = 0; i < 4; i++) out_align[b * TT + tid + i * 256] = e[i] * inv;
}

// ---------------- K_context: context[b,a] = sum_t align[b,t] * v[b,t,a] (v in f16) ----------------
__global__ void k_context(const float* __restrict__ align, const _Float16* __restrict__ v_ws,
                          float* __restrict__ out_ctx) {
    int b = blockIdx.y, t0 = blockIdx.x * 64, tid = threadIdx.x;
    int a0 = (tid & 31) * 4, tl = tid >> 5;
    __shared__ float sh[8 * 132];
    f32x4_t acc = (f32x4_t){0.f, 0.f, 0.f, 0.f};
    for (int tt = tl; tt < 64; tt += 8) {
        float w = align[b * TT + t0 + tt];
        f16x4_t vv = *(const f16x4_t*)(v_ws + (size_t)(b * TT + t0 + tt) * AA + a0);
        acc[0] += w * (float)vv[0];
        acc[1] += w * (float)vv[1];
        acc[2] += w * (float)vv[2];
        acc[3] += w * (float)vv[3];
    }
    *(f32x4_t*)&sh[tl * 132 + a0] = acc;
    __syncthreads();
    if (tid < 128) {
        float s = 0.f;
#pragma unroll
        for (int j = 0; j < 8; j++) s += sh[j * 132 + tid];
        atomicAdd(out_ctx + b * AA + tid, s);
    }
}

extern "C" void kernel_launch(void* const* d_in, const int* in_sizes, int n_in,
                              void* d_out, int out_size, void* d_ws, size_t ws_size,
                              hipStream_t stream) {
    const float* query = (const float*)d_in[0];
    const float* value = (const float*)d_in[1];
    const float* xcat  = (const float*)d_in[2];
    const float* Wq    = (const float*)d_in[3];
    const float* Wm    = (const float*)d_in[4];
    const float* Wv    = (const float*)d_in[5];
    const float* Wconv = (const float*)d_in[6];
    const float* Wloc  = (const float*)d_in[7];
    float* out = (float*)d_out;

    float* ws = (float*)d_ws;
    float* q_ws  = ws;                            // 8192 f
    float* sc_ws = q_ws + 8192;                   // 65536 f
    _Float16* v_ws = (_Float16*)(sc_ws + 65536);  // 8388608 halfs = 4194304 f
    __bf16* pwmhi = (__bf16*)(sc_ws + 65536 + 4194304);
    __bf16* pwmlo = pwmhi + 65536;
    __bf16* wcthi = pwmlo + 65536;
    __bf16* wctlo = wcthi + 65536;
    __bf16* pwlhi = wctlo + 65536;                // 131072
    __bf16* pwllo = pwlhi + 131072;
    float* ztf = (float*)(pwllo + 131072);        // 2 planes x 524288 f32 (4 MB)

    k_prep<<<120, 256, 0, stream>>>(Wm, Wconv, Wloc, query, Wq,
                                    pwmhi, pwmlo, wcthi, wctlo, pwlhi, pwllo, q_ws);
    k_zq<<<256, 256, 0, stream>>>(xcat, pwlhi, pwllo, ztf);
    k_main<<<512, 256, 0, stream>>>(value, pwmhi, pwmlo, wcthi, wctlo, ztf,
                                    q_ws, Wv, v_ws, sc_ws);
    k_softmax<<<BB, 256, 0, stream>>>(sc_ws, out + 8192, out);
    k_context<<<dim3(16, BB), 256, 0, stream>>>(out + 8192, v_ws, out);
}